// Round 8
// baseline (216.164 us; speedup 1.0000x reference)
//
#include <hip/hip_runtime.h>
#include <math.h>

#define H 64
// ws layout (floats):
//   [64..319]  64 x float4 fuse params: {base, sc0, sc1, w2}
//   [384..]    encoder partials: (eb+nb) x 64 (edge blocks first, then node)
#define WS_FUSE 64
#define WS_PART 384
#define LOG2E 1.4426950408889634f

// opaque register pin: compiler cannot rematerialize/sink the producing load
#define PIN(x) asm volatile("" : "+v"(x))
#define PIN4(v) { PIN(v.x); PIN(v.y); PIN(v.z); PIN(v.w); }

__device__ __forceinline__ float fast_sigmoid(float x) {
    float e = exp2f(-LOG2E * x);
    return __builtin_amdgcn_rcpf(1.f + e);
}
__device__ __forceinline__ float fast_tanh(float x) {
    x = fminf(fmaxf(x, -9.f), 9.f);
    float e = exp2f((2.f * LOG2E) * x);
    return (e - 1.f) * __builtin_amdgcn_rcpf(e + 1.f);
}
__device__ __forceinline__ float4 f4fma(float s, float4 a, float4 b) {
    b.x = fmaf(s, a.x, b.x); b.y = fmaf(s, a.y, b.y);
    b.z = fmaf(s, a.z, b.z); b.w = fmaf(s, a.w, b.w); return b;
}
__device__ __forceinline__ float4 f4reluacc(float4 t, float4 a) {
    a.x += fmaxf(t.x, 0.f); a.y += fmaxf(t.y, 0.f);
    a.z += fmaxf(t.z, 0.f); a.w += fmaxf(t.w, 0.f); return a;
}
#define WREDUCE(x) { x += __shfl_xor(x, 1); x += __shfl_xor(x, 2); x += __shfl_xor(x, 4); \
                     x += __shfl_xor(x, 8); x += __shfl_xor(x, 16); x += __shfl_xor(x, 32); }

// ---------------- edge encoder: relu(X @ W + b), K=5, named regs only ----------------
__device__ void encode_edge(const float* __restrict__ X, const float* __restrict__ Wg,
                            const float* __restrict__ bias, int nrows,
                            int blk, int nblk, float* __restrict__ out, float* __restrict__ xs)
{
    int tid = threadIdx.x, lane = tid & 63, s = tid >> 6;
    int j0 = s * 8;
    float4 wa0 = *(const float4*)(Wg + 0*H + j0), wb0 = *(const float4*)(Wg + 0*H + j0 + 4);
    float4 wa1 = *(const float4*)(Wg + 1*H + j0), wb1 = *(const float4*)(Wg + 1*H + j0 + 4);
    float4 wa2 = *(const float4*)(Wg + 2*H + j0), wb2 = *(const float4*)(Wg + 2*H + j0 + 4);
    float4 wa3 = *(const float4*)(Wg + 3*H + j0), wb3 = *(const float4*)(Wg + 3*H + j0 + 4);
    float4 wa4 = *(const float4*)(Wg + 4*H + j0), wb4 = *(const float4*)(Wg + 4*H + j0 + 4);
    float4 bia = *(const float4*)(bias + j0),     bib = *(const float4*)(bias + j0 + 4);
    PIN4(wa0) PIN4(wb0) PIN4(wa1) PIN4(wb1) PIN4(wa2) PIN4(wb2)
    PIN4(wa3) PIN4(wb3) PIN4(wa4) PIN4(wb4)
    float4 acca = {0.f,0.f,0.f,0.f}, accb = {0.f,0.f,0.f,0.f};

    int ntiles = (nrows + 255) >> 8;
    for (int tile = blk; tile < ntiles; tile += nblk) {
        long base = (long)tile << 8;
        int rem = (int)(nrows - base);
        int cnt = rem > 256 ? 256 : rem;
        int nw = cnt * 5;
        __syncthreads();
        const float* Xb = X + base * 5;
        int n4 = nw >> 2;
        for (int idx = tid; idx < n4; idx += 512) ((float4*)xs)[idx] = ((const float4*)Xb)[idx];
        for (int idx = (n4 << 2) + tid; idx < nw; idx += 512) xs[idx] = Xb[idx];
        __syncthreads();
#pragma unroll
        for (int ri = 0; ri < 4; ++ri) {
            int r = ri * 64 + lane;
            if (r < cnt) {
                float x0 = xs[r*5+0], x1 = xs[r*5+1], x2 = xs[r*5+2], x3 = xs[r*5+3], x4 = xs[r*5+4];
                float4 ta = bia, tb = bib;
                ta = f4fma(x0, wa0, ta); tb = f4fma(x0, wb0, tb);
                ta = f4fma(x1, wa1, ta); tb = f4fma(x1, wb1, tb);
                ta = f4fma(x2, wa2, ta); tb = f4fma(x2, wb2, tb);
                ta = f4fma(x3, wa3, ta); tb = f4fma(x3, wb3, tb);
                ta = f4fma(x4, wa4, ta); tb = f4fma(x4, wb4, tb);
                acca = f4reluacc(ta, acca); accb = f4reluacc(tb, accb);
            }
        }
    }
    WREDUCE(acca.x) WREDUCE(acca.y) WREDUCE(acca.z) WREDUCE(acca.w)
    WREDUCE(accb.x) WREDUCE(accb.y) WREDUCE(accb.z) WREDUCE(accb.w)
    if (lane == 0) {
        *(float4*)(out + j0) = acca;
        *(float4*)(out + j0 + 4) = accb;
    }
}

// ---------------- node encoder: K=2 ----------------
__device__ void encode_node(const float* __restrict__ X, const float* __restrict__ Wg,
                            const float* __restrict__ bias, int nrows,
                            int blk, int nblk, float* __restrict__ out, float* __restrict__ xs)
{
    int tid = threadIdx.x, lane = tid & 63, s = tid >> 6;
    int j0 = s * 8;
    float4 wa0 = *(const float4*)(Wg + 0*H + j0), wb0 = *(const float4*)(Wg + 0*H + j0 + 4);
    float4 wa1 = *(const float4*)(Wg + 1*H + j0), wb1 = *(const float4*)(Wg + 1*H + j0 + 4);
    float4 bia = *(const float4*)(bias + j0),     bib = *(const float4*)(bias + j0 + 4);
    PIN4(wa0) PIN4(wb0) PIN4(wa1) PIN4(wb1)
    float4 acca = {0.f,0.f,0.f,0.f}, accb = {0.f,0.f,0.f,0.f};

    int ntiles = (nrows + 255) >> 8;
    for (int tile = blk; tile < ntiles; tile += nblk) {
        long base = (long)tile << 8;
        int rem = (int)(nrows - base);
        int cnt = rem > 256 ? 256 : rem;
        int nw = cnt * 2;
        __syncthreads();
        const float* Xb = X + base * 2;
        int n4 = nw >> 2;
        for (int idx = tid; idx < n4; idx += 512) ((float4*)xs)[idx] = ((const float4*)Xb)[idx];
        for (int idx = (n4 << 2) + tid; idx < nw; idx += 512) xs[idx] = Xb[idx];
        __syncthreads();
#pragma unroll
        for (int ri = 0; ri < 4; ++ri) {
            int r = ri * 64 + lane;
            if (r < cnt) {
                float x0 = xs[r*2+0], x1 = xs[r*2+1];
                float4 ta = bia, tb = bib;
                ta = f4fma(x0, wa0, ta); tb = f4fma(x0, wb0, tb);
                ta = f4fma(x1, wa1, ta); tb = f4fma(x1, wb1, tb);
                acca = f4reluacc(ta, acca); accb = f4reluacc(tb, accb);
            }
        }
    }
    WREDUCE(acca.x) WREDUCE(acca.y) WREDUCE(acca.z) WREDUCE(acca.w)
    WREDUCE(accb.x) WREDUCE(accb.y) WREDUCE(accb.z) WREDUCE(accb.w)
    if (lane == 0) {
        *(float4*)(out + j0) = acca;
        *(float4*)(out + j0 + 4) = accb;
    }
}

__global__ __launch_bounds__(512, 2)
void k_encode(const float* __restrict__ node_feats, const float* __restrict__ edge_feats,
              const float* __restrict__ node_W, const float* __restrict__ node_b,
              const float* __restrict__ edge_W, const float* __restrict__ edge_b,
              int Nn, int Ne, int eb, int nb, float* __restrict__ ws)
{
    __shared__ __align__(16) float xs[1280];   // 256 rows * 5
    int b = blockIdx.x;
    if (b < eb) {
        encode_edge(edge_feats, edge_W, edge_b, Ne, b, eb,
                    ws + WS_PART + (size_t)b * H, xs);
    } else {
        encode_node(node_feats, node_W, node_b, Nn, b - eb, nb,
                    ws + WS_PART + (size_t)b * H, xs);
    }
}

// one 4-FMA group of the 64-dot: uniform-address float4 broadcast from LDS
#define GD(i, wreg, acc) { float4 hb = hbp[i]; \
    acc = fmaf((wreg).w, hb.w, fmaf((wreg).z, hb.z, fmaf((wreg).y, hb.y, fmaf((wreg).x, hb.x, acc)))); }

// ---------------- LSTM: 1 block, 4 waves (wave w = gate w), + finalize ----------------
__global__ __launch_bounds__(256, 1) __attribute__((amdgpu_waves_per_eu(1)))
void k_lstm(const float* __restrict__ hist,
            const float* __restrict__ Wih, const float* __restrict__ Whh,
            const float* __restrict__ bih, const float* __restrict__ bhh,
            const float* __restrict__ W1, const float* __restrict__ b1,
            const float* __restrict__ W2,
            float inv_n, float inv_e, float inv_denom,
            int T, int eb, int nb, float* __restrict__ ws)
{
    __shared__ float hbuf[128];               // [2][64] h double-buffer
    __shared__ float act[512];                // [2][4][64] SoA activations
    __shared__ float hist_s[608];
    __shared__ float hz[64];
    __shared__ __align__(16) float fin[960];
    int tid = threadIdx.x;
    int wv = tid >> 6, j = tid & 63;
    int row = (wv << 6) + j;                  // gate row (i,f,g,o order)

    // 16 NAMED float4 = Whh[row][0..63], PINNED into VGPRs (r7: compiler sank
    // these loads into the loop -> 64KB/step L1-thrash; VGPR_Count was 52)
    const float* wr = Whh + (size_t)row * H;
    float4 w0  = *(const float4*)(wr +  0), w1  = *(const float4*)(wr +  4);
    float4 w2  = *(const float4*)(wr +  8), w3  = *(const float4*)(wr + 12);
    float4 w4  = *(const float4*)(wr + 16), w5  = *(const float4*)(wr + 20);
    float4 w6  = *(const float4*)(wr + 24), w7  = *(const float4*)(wr + 28);
    float4 w8  = *(const float4*)(wr + 32), w9  = *(const float4*)(wr + 36);
    float4 w10 = *(const float4*)(wr + 40), w11 = *(const float4*)(wr + 44);
    float4 w12 = *(const float4*)(wr + 48), w13 = *(const float4*)(wr + 52);
    float4 w14 = *(const float4*)(wr + 56), w15 = *(const float4*)(wr + 60);
    PIN4(w0)  PIN4(w1)  PIN4(w2)  PIN4(w3)  PIN4(w4)  PIN4(w5)  PIN4(w6)  PIN4(w7)
    PIN4(w8)  PIN4(w9)  PIN4(w10) PIN4(w11) PIN4(w12) PIN4(w13) PIN4(w14) PIN4(w15)
    float wi0 = Wih[row*3+0], wi1 = Wih[row*3+1], wi2 = Wih[row*3+2];
    float bs = bih[row] + bhh[row];
    PIN(wi0); PIN(wi1); PIN(wi2); PIN(bs);

    for (int idx = tid; idx < T * 3; idx += 256) hist_s[idx] = hist[idx];
    if (tid < 128) hbuf[tid] = 0.f;
    float c = 0.f, h = 0.f;
    __syncthreads();
    float x0 = hist_s[0], x1 = hist_s[1], x2 = hist_s[2];

    for (int t = 0; t < T; ++t) {
        int p = t & 1;
        const float4* hbp = (const float4*)(hbuf + (p << 6));
        float aA = 0.f, aB = 0.f, aC = 0.f, aD = 0.f;
        GD(0, w0, aA)  GD(1, w1, aB)  GD(2, w2, aC)  GD(3, w3, aD)
        GD(4, w4, aA)  GD(5, w5, aB)  GD(6, w6, aC)  GD(7, w7, aD)
        GD(8, w8, aA)  GD(9, w9, aB)  GD(10, w10, aC) GD(11, w11, aD)
        GD(12, w12, aA) GD(13, w13, aB) GD(14, w14, aC) GD(15, w15, aD)
        float g = ((aA + aB) + (aC + aD)) + fmaf(wi2, x2, fmaf(wi1, x1, fmaf(wi0, x0, bs)));
        float av = (wv == 2) ? fast_tanh(g) : fast_sigmoid(g);   // wave-uniform branch
        act[(p << 8) + row] = av;                                // b32 stride-1: conflict-free
        if (t + 1 < T) { x0 = hist_s[3*t+3]; x1 = hist_s[3*t+4]; x2 = hist_s[3*t+5]; }
        __syncthreads();                                         // the ONLY barrier per step
        float gi = act[(p << 8) + j];                            // SoA b32 stride-1 reads
        float gf = act[(p << 8) + 64 + j];
        float gg = act[(p << 8) + 128 + j];
        float go = act[(p << 8) + 192 + j];
        c = fmaf(gf, c, gi * gg);
        h = go * fast_tanh(c);                                   // redundant in all 4 waves
        hbuf[((p ^ 1) << 6) + j] = h;    // every wave rewrites full row -> own-wave visibility
    }
    if (wv == 0) hz[j] = h;
    __syncthreads();

    // ---- finalize: reduce encoder partials (stream-ordered after k_encode) ----
    {
        float* tmpe = fin;            // [4][64]
        float* tmpn = fin + 256;      // [4][64]
        float* ctx  = fin + 512;      // [192]
        float* pt   = fin + 704;      // [4][64]
        const float* wsp = ws + WS_PART;

        float se = 0.f;
        for (int b = wv; b < eb; b += 4) se += wsp[(size_t)b * H + j];
        tmpe[(wv << 6) + j] = se;
        float sn = 0.f;
        for (int b = wv; b < nb; b += 4) sn += wsp[(size_t)(eb + b) * H + j];
        tmpn[(wv << 6) + j] = sn;
        __syncthreads();

        if (tid < H) {
            float s1 = (tmpn[tid] + tmpn[64 + tid]) + (tmpn[128 + tid] + tmpn[192 + tid]);
            float s2 = (tmpe[tid] + tmpe[64 + tid]) + (tmpe[128 + tid] + tmpe[192 + tid]);
            ctx[tid]       = s1 * inv_n;
            ctx[64 + tid]  = s2 * inv_e;
            ctx[128 + tid] = hz[tid];
        }
        __syncthreads();

        float p = 0.f;
#pragma unroll
        for (int kk = 0; kk < 48; ++kk) {
            int k = wv * 48 + kk;
            p = fmaf(ctx[k], W1[(size_t)k * H + j], p);
        }
        pt[(wv << 6) + j] = p;
        __syncthreads();

        if (tid < H) {
            float bse = b1[tid] + (pt[tid] + pt[64 + tid]) + (pt[128 + tid] + pt[192 + tid]);
            float4 v;
            v.x = bse;
            v.y = W1[(size_t)192 * H + tid] * inv_denom;
            v.z = W1[(size_t)193 * H + tid] * inv_denom;
            v.w = W2[tid];
            ((float4*)(ws + WS_FUSE))[tid] = v;
        }
    }
}

// ---------------- per-pair fused MLP score, 8 pairs/thread ----------------
__global__ __launch_bounds__(256)
void k_fuse(const int* __restrict__ pairs, const float* __restrict__ fb2,
            const float* __restrict__ ws, float* __restrict__ out, int P)
{
    __shared__ __align__(16) float4 sf[H];
    int tid = threadIdx.x;
    if (tid < H) sf[tid] = ((const float4*)(ws + WS_FUSE))[tid];
    __syncthreads();

    int i0 = blockIdx.x * 2048 + tid;
    float bias = fb2[0];
    float p0[8], p1[8], sc[8];
#pragma unroll
    for (int q = 0; q < 8; ++q) {
        int i = i0 + q * 256;
        int2 pr = (i < P) ? ((const int2*)pairs)[i] : make_int2(0, 0);
        p0[q] = (float)pr.x; p1[q] = (float)pr.y; sc[q] = bias;
    }
#pragma unroll
    for (int jj = 0; jj < H; ++jj) {
        float4 v = sf[jj];
#pragma unroll
        for (int q = 0; q < 8; ++q) {
            float hh = fmaf(p1[q], v.z, fmaf(p0[q], v.y, v.x));
            sc[q] = fmaf(fmaxf(hh, 0.f), v.w, sc[q]);
        }
    }
#pragma unroll
    for (int q = 0; q < 8; ++q) {
        int i = i0 + q * 256;
        if (i < P) out[i] = sc[q];
    }
}

extern "C" void kernel_launch(void* const* d_in, const int* in_sizes, int n_in,
                              void* d_out, int out_size, void* d_ws, size_t ws_size,
                              hipStream_t stream) {
    const float* node_feats = (const float*)d_in[0];
    const float* edge_feats = (const float*)d_in[1];
    const float* hist       = (const float*)d_in[2];
    const int*   pairs      = (const int*)d_in[3];
    // d_in[4] = N scalar (== node row count)
    const float* node_W = (const float*)d_in[5];
    const float* node_b = (const float*)d_in[6];
    const float* edge_W = (const float*)d_in[7];
    const float* edge_b = (const float*)d_in[8];
    const float* Wih    = (const float*)d_in[9];
    const float* Whh    = (const float*)d_in[10];
    const float* bih    = (const float*)d_in[11];
    const float* bhh    = (const float*)d_in[12];
    const float* W1     = (const float*)d_in[13];
    const float* b1     = (const float*)d_in[14];
    const float* W2     = (const float*)d_in[15];
    const float* b2     = (const float*)d_in[16];

    int Nn = in_sizes[0] / 2;
    int Ne = in_sizes[1] / 5;
    int T  = in_sizes[2] / 3;
    int P  = in_sizes[3] / 2;

    // 448 + 64 = 512 blocks -> fully co-resident at 2 blocks/CU
    int eb = 448, nb = 64;
    while ((size_t)(WS_PART + (eb + nb) * H) * sizeof(float) > ws_size && eb > 8) {
        eb >>= 1; if (nb > 4) nb >>= 1;
    }

    float inv_n = (float)(1.0 / (double)Nn);
    float inv_e = (float)(1.0 / (double)Ne);
    float denomf = (float)(Nn - 1) + 1e-9f;
    float inv_denom = 1.0f / denomf;

    float* ws = (float*)d_ws;

    k_encode<<<eb + nb, 512, 0, stream>>>(
        node_feats, edge_feats, node_W, node_b, edge_W, edge_b,
        Nn, Ne, eb, nb, ws);

    k_lstm<<<1, 256, 0, stream>>>(
        hist, Wih, Whh, bih, bhh, W1, b1, W2,
        inv_n, inv_e, inv_denom, T, eb, nb, ws);

    int blocksC = (P + 2047) / 2048;
    k_fuse<<<blocksC, 256, 0, stream>>>(pairs, b2, ws, (float*)d_out, P);
}

// Round 9
// 181.648 us; speedup vs baseline: 1.1900x; 1.1900x over previous
//
#include <hip/hip_runtime.h>
#include <math.h>

#define H 64
// ws layout (floats):
//   [64..319]  64 x float4 fuse params: {base, sc0, sc1, w2}
//   [384..]    encoder partials: (eb+nb) x 64 (edge blocks first, then node)
#define WS_FUSE 64
#define WS_PART 384
#define LOG2E 1.4426950408889634f

// opaque register pin
#define PIN(x) asm volatile("" : "+v"(x))
#define PIN4(v) { PIN(v.x); PIN(v.y); PIN(v.z); PIN(v.w); }

__device__ __forceinline__ float fast_sigmoid(float x) {
    float e = exp2f(-LOG2E * x);
    return __builtin_amdgcn_rcpf(1.f + e);
}
__device__ __forceinline__ float fast_tanh(float x) {
    x = fminf(fmaxf(x, -9.f), 9.f);
    float e = exp2f((2.f * LOG2E) * x);
    return (e - 1.f) * __builtin_amdgcn_rcpf(e + 1.f);
}
__device__ __forceinline__ float4 f4fma(float s, float4 a, float4 b) {
    b.x = fmaf(s, a.x, b.x); b.y = fmaf(s, a.y, b.y);
    b.z = fmaf(s, a.z, b.z); b.w = fmaf(s, a.w, b.w); return b;
}
__device__ __forceinline__ float4 f4reluacc(float4 t, float4 a) {
    a.x += fmaxf(t.x, 0.f); a.y += fmaxf(t.y, 0.f);
    a.z += fmaxf(t.z, 0.f); a.w += fmaxf(t.w, 0.f); return a;
}
#define WREDUCE(x) { x += __shfl_xor(x, 1); x += __shfl_xor(x, 2); x += __shfl_xor(x, 4); \
                     x += __shfl_xor(x, 8); x += __shfl_xor(x, 16); x += __shfl_xor(x, 32); }

// ---------------- edge encoder: relu(X @ W + b), K=5 (unchanged from r8) ----------------
__device__ void encode_edge(const float* __restrict__ X, const float* __restrict__ Wg,
                            const float* __restrict__ bias, int nrows,
                            int blk, int nblk, float* __restrict__ out, float* __restrict__ xs)
{
    int tid = threadIdx.x, lane = tid & 63, s = tid >> 6;
    int j0 = s * 8;
    float4 wa0 = *(const float4*)(Wg + 0*H + j0), wb0 = *(const float4*)(Wg + 0*H + j0 + 4);
    float4 wa1 = *(const float4*)(Wg + 1*H + j0), wb1 = *(const float4*)(Wg + 1*H + j0 + 4);
    float4 wa2 = *(const float4*)(Wg + 2*H + j0), wb2 = *(const float4*)(Wg + 2*H + j0 + 4);
    float4 wa3 = *(const float4*)(Wg + 3*H + j0), wb3 = *(const float4*)(Wg + 3*H + j0 + 4);
    float4 wa4 = *(const float4*)(Wg + 4*H + j0), wb4 = *(const float4*)(Wg + 4*H + j0 + 4);
    float4 bia = *(const float4*)(bias + j0),     bib = *(const float4*)(bias + j0 + 4);
    PIN4(wa0) PIN4(wb0) PIN4(wa1) PIN4(wb1) PIN4(wa2) PIN4(wb2)
    PIN4(wa3) PIN4(wb3) PIN4(wa4) PIN4(wb4)
    float4 acca = {0.f,0.f,0.f,0.f}, accb = {0.f,0.f,0.f,0.f};

    int ntiles = (nrows + 255) >> 8;
    for (int tile = blk; tile < ntiles; tile += nblk) {
        long base = (long)tile << 8;
        int rem = (int)(nrows - base);
        int cnt = rem > 256 ? 256 : rem;
        int nw = cnt * 5;
        __syncthreads();
        const float* Xb = X + base * 5;
        int n4 = nw >> 2;
        for (int idx = tid; idx < n4; idx += 512) ((float4*)xs)[idx] = ((const float4*)Xb)[idx];
        for (int idx = (n4 << 2) + tid; idx < nw; idx += 512) xs[idx] = Xb[idx];
        __syncthreads();
#pragma unroll
        for (int ri = 0; ri < 4; ++ri) {
            int r = ri * 64 + lane;
            if (r < cnt) {
                float x0 = xs[r*5+0], x1 = xs[r*5+1], x2 = xs[r*5+2], x3 = xs[r*5+3], x4 = xs[r*5+4];
                float4 ta = bia, tb = bib;
                ta = f4fma(x0, wa0, ta); tb = f4fma(x0, wb0, tb);
                ta = f4fma(x1, wa1, ta); tb = f4fma(x1, wb1, tb);
                ta = f4fma(x2, wa2, ta); tb = f4fma(x2, wb2, tb);
                ta = f4fma(x3, wa3, ta); tb = f4fma(x3, wb3, tb);
                ta = f4fma(x4, wa4, ta); tb = f4fma(x4, wb4, tb);
                acca = f4reluacc(ta, acca); accb = f4reluacc(tb, accb);
            }
        }
    }
    WREDUCE(acca.x) WREDUCE(acca.y) WREDUCE(acca.z) WREDUCE(acca.w)
    WREDUCE(accb.x) WREDUCE(accb.y) WREDUCE(accb.z) WREDUCE(accb.w)
    if (lane == 0) {
        *(float4*)(out + j0) = acca;
        *(float4*)(out + j0 + 4) = accb;
    }
}

// ---------------- node encoder: K=2 (unchanged) ----------------
__device__ void encode_node(const float* __restrict__ X, const float* __restrict__ Wg,
                            const float* __restrict__ bias, int nrows,
                            int blk, int nblk, float* __restrict__ out, float* __restrict__ xs)
{
    int tid = threadIdx.x, lane = tid & 63, s = tid >> 6;
    int j0 = s * 8;
    float4 wa0 = *(const float4*)(Wg + 0*H + j0), wb0 = *(const float4*)(Wg + 0*H + j0 + 4);
    float4 wa1 = *(const float4*)(Wg + 1*H + j0), wb1 = *(const float4*)(Wg + 1*H + j0 + 4);
    float4 bia = *(const float4*)(bias + j0),     bib = *(const float4*)(bias + j0 + 4);
    PIN4(wa0) PIN4(wb0) PIN4(wa1) PIN4(wb1)
    float4 acca = {0.f,0.f,0.f,0.f}, accb = {0.f,0.f,0.f,0.f};

    int ntiles = (nrows + 255) >> 8;
    for (int tile = blk; tile < ntiles; tile += nblk) {
        long base = (long)tile << 8;
        int rem = (int)(nrows - base);
        int cnt = rem > 256 ? 256 : rem;
        int nw = cnt * 2;
        __syncthreads();
        const float* Xb = X + base * 2;
        int n4 = nw >> 2;
        for (int idx = tid; idx < n4; idx += 512) ((float4*)xs)[idx] = ((const float4*)Xb)[idx];
        for (int idx = (n4 << 2) + tid; idx < nw; idx += 512) xs[idx] = Xb[idx];
        __syncthreads();
#pragma unroll
        for (int ri = 0; ri < 4; ++ri) {
            int r = ri * 64 + lane;
            if (r < cnt) {
                float x0 = xs[r*2+0], x1 = xs[r*2+1];
                float4 ta = bia, tb = bib;
                ta = f4fma(x0, wa0, ta); tb = f4fma(x0, wb0, tb);
                ta = f4fma(x1, wa1, ta); tb = f4fma(x1, wb1, tb);
                acca = f4reluacc(ta, acca); accb = f4reluacc(tb, accb);
            }
        }
    }
    WREDUCE(acca.x) WREDUCE(acca.y) WREDUCE(acca.z) WREDUCE(acca.w)
    WREDUCE(accb.x) WREDUCE(accb.y) WREDUCE(accb.z) WREDUCE(accb.w)
    if (lane == 0) {
        *(float4*)(out + j0) = acca;
        *(float4*)(out + j0 + 4) = accb;
    }
}

__global__ __launch_bounds__(512, 2)
void k_encode(const float* __restrict__ node_feats, const float* __restrict__ edge_feats,
              const float* __restrict__ node_W, const float* __restrict__ node_b,
              const float* __restrict__ edge_W, const float* __restrict__ edge_b,
              int Nn, int Ne, int eb, int nb, float* __restrict__ ws)
{
    __shared__ __align__(16) float xs[1280];
    int b = blockIdx.x;
    if (b < eb) {
        encode_edge(edge_feats, edge_W, edge_b, Ne, b, eb,
                    ws + WS_PART + (size_t)b * H, xs);
    } else {
        encode_node(node_feats, node_W, node_b, Nn, b - eb, nb,
                    ws + WS_PART + (size_t)b * H, xs);
    }
}

// ---------------- LSTM: 1024 threads = 256 gate-rows x 4 k-segments ----------------
// Per-thread live state ~36 floats -> fits ANY VGPR budget, nothing to spill.
__global__ __launch_bounds__(1024, 1)
void k_lstm(const float* __restrict__ hist,
            const float* __restrict__ Wih, const float* __restrict__ Whh,
            const float* __restrict__ bih, const float* __restrict__ bhh,
            const float* __restrict__ W1, const float* __restrict__ b1,
            const float* __restrict__ W2,
            float inv_n, float inv_e, float inv_denom,
            int T, int eb, int nb, float* __restrict__ ws)
{
    __shared__ float p_sh[1024];              // partials [seg][gate*64+j]
    __shared__ __align__(16) float hvec[64];  // current h
    __shared__ float hist_s[608];
    __shared__ __align__(16) float fin[3264]; // finalize scratch (16-wave)
    int tid = threadIdx.x;
    int seg = tid >> 8;                       // 0..3 (wave-uniform: tid>>8 const per wave)
    int row = tid & 255;                      // gate*64 + j
    int kb  = seg << 4;

    // 4 named float4 of Whh[row][16*seg .. +16) -- only 16 weight regs/thread
    const float* wr = Whh + (size_t)row * H + kb;
    float4 w0 = *(const float4*)(wr + 0),  w1 = *(const float4*)(wr + 4);
    float4 w2 = *(const float4*)(wr + 8),  w3 = *(const float4*)(wr + 12);
    PIN4(w0) PIN4(w1) PIN4(w2) PIN4(w3)
    float wi0 = Wih[row*3+0], wi1 = Wih[row*3+1], wi2 = Wih[row*3+2];
    float bs  = bih[row] + bhh[row];
    PIN(wi0); PIN(wi1); PIN(wi2); PIN(bs);

    for (int idx = tid; idx < T * 3; idx += 1024) hist_s[idx] = hist[idx];
    if (tid < 64) hvec[tid] = 0.f;
    float c = 0.f, h = 0.f;                   // meaningful in wave 0 only
    __syncthreads();
    float x0 = hist_s[0], x1 = hist_s[1], x2 = hist_s[2];

    for (int t = 0; t < T; ++t) {
        // ---- phase 1 (all 16 waves): 16-FMA partial dot; h via uniform-address bcast ----
        const float4* hb = (const float4*)(hvec + kb);
        float4 h0 = hb[0], h1 = hb[1], h2 = hb[2], h3 = hb[3];
        float aA = fmaf(w0.w, h0.w, fmaf(w0.z, h0.z, fmaf(w0.y, h0.y, w0.x * h0.x)));
        float aB = fmaf(w1.w, h1.w, fmaf(w1.z, h1.z, fmaf(w1.y, h1.y, w1.x * h1.x)));
        float aC = fmaf(w2.w, h2.w, fmaf(w2.z, h2.z, fmaf(w2.y, h2.y, w2.x * h2.x)));
        float aD = fmaf(w3.w, h3.w, fmaf(w3.z, h3.z, fmaf(w3.y, h3.y, w3.x * h3.x)));
        float a = (aA + aB) + (aC + aD);
        if (seg == 0)                          // fold Wih*x + bias into seg-0 partial
            a += fmaf(wi2, x2, fmaf(wi1, x1, fmaf(wi0, x0, bs)));
        p_sh[tid] = a;                         // stride-1 b32: conflict-free
        if (t + 1 < T) { x0 = hist_s[3*t+3]; x1 = hist_s[3*t+4]; x2 = hist_s[3*t+5]; }
        __syncthreads();                       // barrier A: partials visible

        // ---- phase 2 (wave 0 only): gather 16 partials, activate, update c/h ----
        if (tid < 64) {
            int j = tid;
            float gi = (p_sh[j]       + p_sh[256 + j]) + (p_sh[512 + j] + p_sh[768 + j]);
            float gf = (p_sh[64 + j]  + p_sh[320 + j]) + (p_sh[576 + j] + p_sh[832 + j]);
            float gg = (p_sh[128 + j] + p_sh[384 + j]) + (p_sh[640 + j] + p_sh[896 + j]);
            float go = (p_sh[192 + j] + p_sh[448 + j]) + (p_sh[704 + j] + p_sh[960 + j]);
            gi = fast_sigmoid(gi); gf = fast_sigmoid(gf);
            gg = fast_tanh(gg);    go = fast_sigmoid(go);
            c = fmaf(gf, c, gi * gg);
            h = go * fast_tanh(c);
            hvec[j] = h;
        }
        __syncthreads();                       // barrier B: h(t+1) visible
    }

    // ---- finalize: reduce encoder partials, build fuse params (16 waves) ----
    {
        float* tmpe = fin;            // [16][64]
        float* tmpn = fin + 1024;     // [16][64]
        float* ctx  = fin + 2048;     // [192]
        float* pt   = fin + 2240;     // [16][64]
        int q = tid >> 6, j = tid & 63;
        const float* wsp = ws + WS_PART;

        float se = 0.f;
        for (int b = q; b < eb; b += 16) se += wsp[(size_t)b * H + j];
        tmpe[(q << 6) + j] = se;
        float sn = 0.f;
        for (int b = q; b < nb; b += 16) sn += wsp[(size_t)(eb + b) * H + j];
        tmpn[(q << 6) + j] = sn;
        __syncthreads();

        if (tid < 64) {
            float s1 = 0.f, s2 = 0.f;
#pragma unroll
            for (int r = 0; r < 16; ++r) { s1 += tmpn[(r << 6) + tid]; s2 += tmpe[(r << 6) + tid]; }
            ctx[tid]       = s1 * inv_n;
            ctx[64 + tid]  = s2 * inv_e;
            ctx[128 + tid] = hvec[tid];
        }
        __syncthreads();

        float p = 0.f;
#pragma unroll
        for (int kk = 0; kk < 12; ++kk) {
            int k = q * 12 + kk;
            p = fmaf(ctx[k], W1[(size_t)k * H + j], p);
        }
        pt[(q << 6) + j] = p;
        __syncthreads();

        if (tid < 64) {
            float bse = b1[tid];
#pragma unroll
            for (int r = 0; r < 16; ++r) bse += pt[(r << 6) + tid];
            float4 v;
            v.x = bse;
            v.y = W1[(size_t)192 * H + tid] * inv_denom;
            v.z = W1[(size_t)193 * H + tid] * inv_denom;
            v.w = W2[tid];
            ((float4*)(ws + WS_FUSE))[tid] = v;
        }
    }
}

// ---------------- per-pair fused MLP score, 8 pairs/thread (unchanged) ----------------
__global__ __launch_bounds__(256)
void k_fuse(const int* __restrict__ pairs, const float* __restrict__ fb2,
            const float* __restrict__ ws, float* __restrict__ out, int P)
{
    __shared__ __align__(16) float4 sf[H];
    int tid = threadIdx.x;
    if (tid < H) sf[tid] = ((const float4*)(ws + WS_FUSE))[tid];
    __syncthreads();

    int i0 = blockIdx.x * 2048 + tid;
    float bias = fb2[0];
    float p0[8], p1[8], sc[8];
#pragma unroll
    for (int q = 0; q < 8; ++q) {
        int i = i0 + q * 256;
        int2 pr = (i < P) ? ((const int2*)pairs)[i] : make_int2(0, 0);
        p0[q] = (float)pr.x; p1[q] = (float)pr.y; sc[q] = bias;
    }
#pragma unroll
    for (int jj = 0; jj < H; ++jj) {
        float4 v = sf[jj];
#pragma unroll
        for (int q = 0; q < 8; ++q) {
            float hh = fmaf(p1[q], v.z, fmaf(p0[q], v.y, v.x));
            sc[q] = fmaf(fmaxf(hh, 0.f), v.w, sc[q]);
        }
    }
#pragma unroll
    for (int q = 0; q < 8; ++q) {
        int i = i0 + q * 256;
        if (i < P) out[i] = sc[q];
    }
}

extern "C" void kernel_launch(void* const* d_in, const int* in_sizes, int n_in,
                              void* d_out, int out_size, void* d_ws, size_t ws_size,
                              hipStream_t stream) {
    const float* node_feats = (const float*)d_in[0];
    const float* edge_feats = (const float*)d_in[1];
    const float* hist       = (const float*)d_in[2];
    const int*   pairs      = (const int*)d_in[3];
    // d_in[4] = N scalar (== node row count)
    const float* node_W = (const float*)d_in[5];
    const float* node_b = (const float*)d_in[6];
    const float* edge_W = (const float*)d_in[7];
    const float* edge_b = (const float*)d_in[8];
    const float* Wih    = (const float*)d_in[9];
    const float* Whh    = (const float*)d_in[10];
    const float* bih    = (const float*)d_in[11];
    const float* bhh    = (const float*)d_in[12];
    const float* W1     = (const float*)d_in[13];
    const float* b1     = (const float*)d_in[14];
    const float* W2     = (const float*)d_in[15];
    const float* b2     = (const float*)d_in[16];

    int Nn = in_sizes[0] / 2;
    int Ne = in_sizes[1] / 5;
    int T  = in_sizes[2] / 3;
    int P  = in_sizes[3] / 2;

    int eb = 448, nb = 64;
    while ((size_t)(WS_PART + (eb + nb) * H) * sizeof(float) > ws_size && eb > 16) {
        eb >>= 1; if (nb > 16) nb >>= 1;
    }

    float inv_n = (float)(1.0 / (double)Nn);
    float inv_e = (float)(1.0 / (double)Ne);
    float denomf = (float)(Nn - 1) + 1e-9f;
    float inv_denom = 1.0f / denomf;

    float* ws = (float*)d_ws;

    k_encode<<<eb + nb, 512, 0, stream>>>(
        node_feats, edge_feats, node_W, node_b, edge_W, edge_b,
        Nn, Ne, eb, nb, ws);

    k_lstm<<<1, 1024, 0, stream>>>(
        hist, Wih, Whh, bih, bhh, W1, b1, W2,
        inv_n, inv_e, inv_denom, T, eb, nb, ws);

    int blocksC = (P + 2047) / 2048;
    k_fuse<<<blocksC, 256, 0, stream>>>(pairs, b2, ws, (float*)d_out, P);
}